// Round 1
// 1309.787 us; speedup vs baseline: 1.0358x; 1.0358x over previous
//
#include <hip/hip_runtime.h>
#include <stdint.h>

#define M_DIM 8192
#define N_DIM 16384
#define K_DIM 4096
#define BK 128  // int8 K-bytes per tile (32 K-tiles)

typedef __attribute__((ext_vector_type(4))) float f32x4;
typedef __attribute__((ext_vector_type(4))) int i32x4;

// ---------------------------------------------------------------------------
// quant_x: per-row dynamic int8 quantization of x. (unchanged — verified)
// ---------------------------------------------------------------------------
__global__ __launch_bounds__(256) void quant_x_kernel(const float* __restrict__ x,
                                                      int* __restrict__ xq,
                                                      float* __restrict__ sx) {
  const int row = blockIdx.x;
  const int t = threadIdx.x;
  const float* xr = x + (size_t)row * K_DIM;
  f32x4 v[4];
#pragma unroll
  for (int c = 0; c < 4; ++c) v[c] = *(const f32x4*)(xr + c * 1024 + t * 4);
  float amax = 0.f;
#pragma unroll
  for (int c = 0; c < 4; ++c)
#pragma unroll
    for (int e = 0; e < 4; ++e) amax = fmaxf(amax, fabsf(v[c][e]));
#pragma unroll
  for (int off = 32; off > 0; off >>= 1)
    amax = fmaxf(amax, __shfl_xor(amax, off, 64));
  __shared__ float wmax[4];
  if ((t & 63) == 0) wmax[t >> 6] = amax;
  __syncthreads();
  amax = fmaxf(fmaxf(wmax[0], wmax[1]), fmaxf(wmax[2], wmax[3]));
  const float inv = amax > 0.f ? 127.f / amax : 0.f;
  if (t == 0) sx[row] = amax * (1.f / 127.f);
  int* xqr = xq + (size_t)row * (K_DIM / 4);
#pragma unroll
  for (int c = 0; c < 4; ++c) {
    int b0 = (int)rintf(v[c][0] * inv) & 255;
    int b1 = (int)rintf(v[c][1] * inv) & 255;
    int b2 = (int)rintf(v[c][2] * inv) & 255;
    int b3 = (int)rintf(v[c][3] * inv) & 255;
    xqr[c * 256 + t] = b0 | (b1 << 8) | (b2 << 16) | (b3 << 24);
  }
}

// ---------------------------------------------------------------------------
// cvt_w8: int32 weights -> packed int8. (unchanged — verified)
// ---------------------------------------------------------------------------
__global__ __launch_bounds__(256) void cvt_w8_kernel(const int* __restrict__ in,
                                                     int* __restrict__ outp,
                                                     int n16) {
  int i = blockIdx.x * 256 + threadIdx.x;
  if (i >= n16) return;
  size_t b = (size_t)i * 16;
  i32x4 o;
#pragma unroll
  for (int c = 0; c < 4; ++c) {
    i32x4 a = *(const i32x4*)(in + b + c * 4);
    o[c] = (a[0] & 255) | ((a[1] & 255) << 8) | ((a[2] & 255) << 16) | ((a[3] & 255) << 24);
  }
  *(i32x4*)(outp + (size_t)i * 4) = o;
}

// async global->LDS, 16B/lane; LDS dest = wave-uniform base + lane*16
__device__ __forceinline__ void async_copy16(const void* g, void* l) {
  __builtin_amdgcn_global_load_lds(
      (__attribute__((address_space(1))) void*)(uintptr_t)g,
      (__attribute__((address_space(3))) void*)l,
      16, 0, 0);
}

#define FENCE() asm volatile("" ::: "memory")
#define BAR()                         \
  do {                                \
    FENCE();                          \
    __builtin_amdgcn_s_barrier();     \
    FENCE();                          \
  } while (0)
#define WAIT_LGKM0()                                      \
  do {                                                    \
    asm volatile("s_waitcnt lgkmcnt(0)" ::: "memory");    \
    __builtin_amdgcn_sched_barrier(0);                    \
  } while (0)

// 16-MFMA cluster: acc[IB..IB+3][JB..JB+1], both K-substeps.
template <int IB, int JB>
__device__ __forceinline__ void mfma_q(const i32x4 (&a)[4][2], const i32x4 (&b)[4][2],
                                       i32x4 (&acc)[8][4]) {
#pragma unroll
  for (int i = 0; i < 4; ++i)
#pragma unroll
    for (int j = 0; j < 2; ++j) {
      acc[IB + i][JB + j] =
          __builtin_amdgcn_mfma_i32_16x16x64_i8(a[i][0], b[JB + j][0], acc[IB + i][JB + j], 0, 0, 0);
      acc[IB + i][JB + j] =
          __builtin_amdgcn_mfma_i32_16x16x64_i8(a[i][1], b[JB + j][1], acc[IB + i][JB + j], 0, 0, 0);
    }
}

// ---------------------------------------------------------------------------
// int8 GEMM, 256x256 tile, BK=128, 8 waves (2Mx4N), 4-phase K-tile schedule
// with counted vmcnt (T3+T4), setprio around MFMA (T5), XOR LDS swizzle (T2).
//
// LDS: A[2][256*128] | B[2][256*128] = 128 KiB (1 block/CU by design).
// Swizzle: 16B slot s of row r stored at slot s ^ ((r>>1)&7); applied on the
// pre-swizzled GLOBAL source (global_load_lds dest is linear) and on the
// ds_read side — both-sides involution (rule #21).
//
// Phases per K-tile (buf = kt&1, 2 barriers each; reads 12/4/8/0):
//  p0: read a[rows 0-3]+b[cols 0-1]; stage A1(kt+1)->buf^1 ; MFMA acc[0..3][0..1]
//  p1: read b[cols 2-3]             ;                        MFMA acc[0..3][2..3]
//  p2: read a[rows 4-7]             ; stage B0(kt+2)->buf  ; MFMA acc[4..7][0..1]
//  p3:                              ; stage A0,B1(kt+2)    ; MFMA acc[4..7][2..3]
//      then s_waitcnt vmcnt(6)  (3 half-tiles in flight; drain-0 only at kt=30)
// Safety: A-half regions of a buffer are last read at p2 (writable from p3),
// B-half regions at p1 (writable from p2); cross-wave visibility via each
// wave's own vmcnt before the phase-ending barrier.
// ---------------------------------------------------------------------------
__global__ __launch_bounds__(512, 2) void gemm_i8_kernel(
    const signed char* __restrict__ A,   // [M,K] int8 (xq)
    const signed char* __restrict__ Wq,  // [N,K] int8
    const float* __restrict__ sx,        // [M]
    const float* __restrict__ scale,     // [N]
    const float* __restrict__ bias,      // [N]
    float* __restrict__ out) {
  __shared__ __attribute__((aligned(16))) signed char lds[131072];
  signed char* ldsA = &lds[0];      // 2 x 32768
  signed char* ldsB = &lds[65536];  // 2 x 32768

  const int tid = threadIdx.x;
  const int wv = tid >> 6;
  const int ln = tid & 63;
  const int l4 = ln & 15;
  const int hi = ln >> 4;
  const int wm = wv >> 2;  // 0..1
  const int wn = wv & 3;   // 0..3

  // Bijective XCD swizzle (nwg=2048 % 8 == 0): each XCD gets 256 consecutive
  // wg = all 32 mi x 8 ni -> B-tile reuse in L2, A fully L3-resident.
  const int wg = (blockIdx.x & 7) * 256 + (blockIdx.x >> 3);
  const int mi = wg & 31;
  const int ni = wg >> 5;
  const int m0 = mi * 256;
  const int n0 = ni * 256;

  // --- staging geometry: one call site = block writes 64 rows x 128 B.
  // thread t -> row (t>>3) within region, physical 16B slot (t&7);
  // global source slot = (t&7) ^ ((r>>1)&7)  (pre-swizzled source).
  const int t8 = tid >> 3;
  const size_t stage_off =
      (size_t)t8 * K_DIM + (size_t)((((tid & 7) ^ ((t8 >> 1) & 7))) << 4);
  const signed char* Asrc = A + (size_t)m0 * K_DIM + stage_off;
  const signed char* Bsrc = Wq + (size_t)n0 * K_DIM + stage_off;

#define STAGE_A(buf, kt, h)                                                      \
  do {                                                                           \
    async_copy16(Asrc + ((size_t)((h) * 128) * K_DIM + (size_t)(kt) * BK),       \
                 ldsA + (buf) * 32768 + (h) * 16384 + wv * 1024);                \
    async_copy16(Asrc + ((size_t)((h) * 128 + 64) * K_DIM + (size_t)(kt) * BK),  \
                 ldsA + (buf) * 32768 + (h) * 16384 + 8192 + wv * 1024);         \
  } while (0)
#define STAGE_B(buf, kt, h)                                                      \
  do {                                                                           \
    async_copy16(Bsrc + ((size_t)((h) * 128) * K_DIM + (size_t)(kt) * BK),       \
                 ldsB + (buf) * 32768 + (h) * 16384 + wv * 1024);                \
    async_copy16(Bsrc + ((size_t)((h) * 128 + 64) * K_DIM + (size_t)(kt) * BK),  \
                 ldsB + (buf) * 32768 + (h) * 16384 + 8192 + wv * 1024);         \
  } while (0)

  // --- fragment read offsets. Lane reads row (base + fi*16 + l4), logical
  // k-chunk g = s*4 + hi; physical = g ^ ((row>>1)&7) = g ^ (l4>>1).
  const int swz = l4 >> 1;
  const int ph0 = (hi ^ swz) * 16;
  const int ph1 = ((4 + hi) ^ swz) * 16;
  const int aoff0 = (wm * 128 + l4) * 128 + ph0;
  const int aoff1 = (wm * 128 + l4) * 128 + ph1;
  const int boff0 = (wn * 64 + l4) * 128 + ph0;
  const int boff1 = (wn * 64 + l4) * 128 + ph1;

  i32x4 acc[8][4];
#pragma unroll
  for (int i = 0; i < 8; ++i)
#pragma unroll
    for (int j = 0; j < 4; ++j) acc[i][j] = (i32x4){0, 0, 0, 0};
  i32x4 a[4][2], b[4][2];

  // --- prologue: all of kt0 (8 loads) + B0,A0,B1 of kt1 (6 loads).
  STAGE_A(0, 0, 0);
  STAGE_A(0, 0, 1);
  STAGE_B(0, 0, 0);
  STAGE_B(0, 0, 1);
  STAGE_B(1, 1, 0);
  STAGE_A(1, 1, 0);
  STAGE_B(1, 1, 1);
  asm volatile("s_waitcnt vmcnt(6)" ::: "memory");  // kt0 landed; kt1 in flight
  BAR();

  for (int kt = 0; kt < 32; ++kt) {
    const int bsel = kt & 1;
    const int nb = bsel ^ 1;
    const signed char* pa = ldsA + bsel * 32768;
    const signed char* pb = ldsB + bsel * 32768;

    // ---- phase 0: A rows 0-3 + B cols 0-1
#pragma unroll
    for (int i = 0; i < 4; ++i) {
      a[i][0] = *(const i32x4*)(pa + aoff0 + i * 2048);
      a[i][1] = *(const i32x4*)(pa + aoff1 + i * 2048);
    }
#pragma unroll
    for (int j = 0; j < 2; ++j) {
      b[j][0] = *(const i32x4*)(pb + boff0 + j * 2048);
      b[j][1] = *(const i32x4*)(pb + boff1 + j * 2048);
    }
    if (kt < 31) STAGE_A(nb, kt + 1, 1);
    BAR();
    WAIT_LGKM0();
    __builtin_amdgcn_s_setprio(1);
    mfma_q<0, 0>(a, b, acc);
    __builtin_amdgcn_s_setprio(0);
    BAR();

    // ---- phase 1: B cols 2-3
#pragma unroll
    for (int j = 2; j < 4; ++j) {
      b[j][0] = *(const i32x4*)(pb + boff0 + j * 2048);
      b[j][1] = *(const i32x4*)(pb + boff1 + j * 2048);
    }
    BAR();
    WAIT_LGKM0();
    __builtin_amdgcn_s_setprio(1);
    mfma_q<0, 2>(a, b, acc);
    __builtin_amdgcn_s_setprio(0);
    BAR();

    // ---- phase 2: A rows 4-7 (B region of this buffer now writable)
#pragma unroll
    for (int i = 0; i < 4; ++i) {
      a[i][0] = *(const i32x4*)(pa + aoff0 + (i + 4) * 2048);
      a[i][1] = *(const i32x4*)(pa + aoff1 + (i + 4) * 2048);
    }
    if (kt < 30) STAGE_B(bsel, kt + 2, 0);
    BAR();
    WAIT_LGKM0();
    __builtin_amdgcn_s_setprio(1);
    mfma_q<4, 0>(a, b, acc);
    __builtin_amdgcn_s_setprio(0);
    BAR();

    // ---- phase 3: no reads (A region of this buffer now writable)
    if (kt < 30) {
      STAGE_A(bsel, kt + 2, 0);
      STAGE_B(bsel, kt + 2, 1);
    }
    __builtin_amdgcn_s_setprio(1);
    mfma_q<4, 2>(a, b, acc);
    __builtin_amdgcn_s_setprio(0);
    if (kt < 30) {
      asm volatile("s_waitcnt vmcnt(6)" ::: "memory");  // next K-tile landed
    } else if (kt == 30) {
      asm volatile("s_waitcnt vmcnt(0)" ::: "memory");  // tail drain
    }
    if (kt < 31) BAR();
  }

  // ---- epilogue. C/D layout: col = l4, row = hi*4 + reg (dtype-independent).
  int colv[4];
  float sc[4], bi[4];
#pragma unroll
  for (int j = 0; j < 4; ++j) {
    colv[j] = n0 + wn * 64 + j * 16 + l4;
    sc[j] = scale[colv[j]];
    bi[j] = bias[colv[j]];
  }
#pragma unroll
  for (int i = 0; i < 8; ++i) {
    const int rowb = m0 + wm * 128 + i * 16 + hi * 4;
    float sxv[4];
#pragma unroll
    for (int r = 0; r < 4; ++r) sxv[r] = sx[rowb + r];
#pragma unroll
    for (int j = 0; j < 4; ++j)
#pragma unroll
      for (int r = 0; r < 4; ++r)
        out[(size_t)(rowb + r) * N_DIM + colv[j]] =
            (float)acc[i][j][r] * sxv[r] * sc[j] + bi[j];
  }
#undef STAGE_A
#undef STAGE_B
}

// Correctness fallback if workspace is too small (not expected to trigger).
__global__ __launch_bounds__(256) void gemm_fallback(
    const float* __restrict__ X, const int* __restrict__ W,
    const float* __restrict__ scale, const float* __restrict__ bias,
    float* __restrict__ out) {
  __shared__ float Xs[64][17];
  __shared__ float Ws[64][17];
  const int tx = threadIdx.x & 15, ty = threadIdx.x >> 4;
  const int m0 = blockIdx.y * 64, n0 = blockIdx.x * 64;
  float acc[4][4] = {};
  for (int k0 = 0; k0 < K_DIM; k0 += 16) {
    for (int t = threadIdx.x; t < 64 * 16; t += 256) {
      int r = t >> 4, c = t & 15;
      Xs[r][c] = X[(size_t)(m0 + r) * K_DIM + k0 + c];
      Ws[r][c] = (float)W[(size_t)(n0 + r) * K_DIM + k0 + c];
    }
    __syncthreads();
#pragma unroll
    for (int kk = 0; kk < 16; ++kk)
#pragma unroll
      for (int i = 0; i < 4; ++i)
#pragma unroll
        for (int j = 0; j < 4; ++j)
          acc[i][j] += Xs[ty * 4 + i][kk] * Ws[tx * 4 + j][kk];
    __syncthreads();
  }
  for (int i = 0; i < 4; ++i)
    for (int j = 0; j < 4; ++j) {
      int row = m0 + ty * 4 + i, col = n0 + tx * 4 + j;
      out[(size_t)row * N_DIM + col] = acc[i][j] * scale[col] + bias[col];
    }
}

extern "C" void kernel_launch(void* const* d_in, const int* in_sizes, int n_in,
                              void* d_out, int out_size, void* d_ws, size_t ws_size,
                              hipStream_t stream) {
  const float* x = (const float*)d_in[0];
  const int* w8 = (const int*)d_in[1];  // integer inputs arrive as int32
  const float* scale = (const float*)d_in[2];
  const float* bias = (const float*)d_in[3];
  float* out = (float*)d_out;

  const size_t xq_bytes = (size_t)M_DIM * K_DIM;  // int8
  const size_t wq_bytes = (size_t)N_DIM * K_DIM;  // int8
  const size_t sx_bytes = (size_t)M_DIM * sizeof(float);
  const size_t need = xq_bytes + wq_bytes + sx_bytes;

  if (ws_size >= need) {
    signed char* xq = (signed char*)d_ws;
    signed char* wq = xq + xq_bytes;
    float* sx = (float*)(wq + wq_bytes);

    quant_x_kernel<<<M_DIM, 256, 0, stream>>>(x, (int*)xq, sx);
    int nw16 = (int)(wq_bytes / 16);
    cvt_w8_kernel<<<(nw16 + 255) / 256, 256, 0, stream>>>(w8, (int*)wq, nw16);
    gemm_i8_kernel<<<(M_DIM / 256) * (N_DIM / 256), 512, 0, stream>>>(
        xq, wq, sx, scale, bias, out);
  } else {
    dim3 grid(N_DIM / 64, M_DIM / 64);
    gemm_fallback<<<grid, 256, 0, stream>>>(x, w8, scale, bias, out);
  }
}

// Round 2
// 1299.599 us; speedup vs baseline: 1.0439x; 1.0078x over previous
//
#include <hip/hip_runtime.h>
#include <stdint.h>

#define M_DIM 8192
#define N_DIM 16384
#define K_DIM 4096
#define BK 128  // int8 K-bytes per tile (32 K-tiles)

typedef __attribute__((ext_vector_type(4))) float f32x4;
typedef __attribute__((ext_vector_type(4))) int i32x4;

// ---------------------------------------------------------------------------
// prep_kernel: fused quant_x (blocks 0..8191) + cvt_w8 (blocks 8192..24575).
// Both paths verified unchanged; fusion overlaps their memory streams and
// saves one launch.
// ---------------------------------------------------------------------------
__global__ __launch_bounds__(256) void prep_kernel(const float* __restrict__ x,
                                                   int* __restrict__ xq,
                                                   float* __restrict__ sx,
                                                   const int* __restrict__ w8,
                                                   int* __restrict__ wq) {
  const int t = threadIdx.x;
  if (blockIdx.x < M_DIM) {
    // ---- quant_x path: per-row dynamic int8 quantization
    const int row = blockIdx.x;
    const float* xr = x + (size_t)row * K_DIM;
    f32x4 v[4];
#pragma unroll
    for (int c = 0; c < 4; ++c) v[c] = *(const f32x4*)(xr + c * 1024 + t * 4);
    float amax = 0.f;
#pragma unroll
    for (int c = 0; c < 4; ++c)
#pragma unroll
      for (int e = 0; e < 4; ++e) amax = fmaxf(amax, fabsf(v[c][e]));
#pragma unroll
    for (int off = 32; off > 0; off >>= 1)
      amax = fmaxf(amax, __shfl_xor(amax, off, 64));
    __shared__ float wmax[4];
    if ((t & 63) == 0) wmax[t >> 6] = amax;
    __syncthreads();
    amax = fmaxf(fmaxf(wmax[0], wmax[1]), fmaxf(wmax[2], wmax[3]));
    const float inv = amax > 0.f ? 127.f / amax : 0.f;
    if (t == 0) sx[row] = amax * (1.f / 127.f);
    int* xqr = xq + (size_t)row * (K_DIM / 4);
#pragma unroll
    for (int c = 0; c < 4; ++c) {
      int b0 = (int)rintf(v[c][0] * inv) & 255;
      int b1 = (int)rintf(v[c][1] * inv) & 255;
      int b2 = (int)rintf(v[c][2] * inv) & 255;
      int b3 = (int)rintf(v[c][3] * inv) & 255;
      xqr[c * 256 + t] = b0 | (b1 << 8) | (b2 << 16) | (b3 << 24);
    }
  } else {
    // ---- cvt_w8 path: int32 weights -> packed int8 (16 ints -> 4 dwords)
    const int i = (blockIdx.x - M_DIM) * 256 + t;
    const int n16 = (int)(((size_t)N_DIM * K_DIM) / 16);
    if (i >= n16) return;
    size_t b = (size_t)i * 16;
    i32x4 o;
#pragma unroll
    for (int c = 0; c < 4; ++c) {
      i32x4 a = *(const i32x4*)(w8 + b + c * 4);
      o[c] = (a[0] & 255) | ((a[1] & 255) << 8) | ((a[2] & 255) << 16) | ((a[3] & 255) << 24);
    }
    *(i32x4*)(wq + (size_t)i * 4) = o;
  }
}

// async global->LDS, 16B/lane; LDS dest = wave-uniform base + lane*16
__device__ __forceinline__ void async_copy16(const void* g, void* l) {
  __builtin_amdgcn_global_load_lds(
      (__attribute__((address_space(1))) void*)(uintptr_t)g,
      (__attribute__((address_space(3))) void*)l,
      16, 0, 0);
}

#define FENCE() asm volatile("" ::: "memory")
#define BAR()                         \
  do {                                \
    FENCE();                          \
    __builtin_amdgcn_s_barrier();     \
    FENCE();                          \
  } while (0)
#define LGKM(n)                                             \
  do {                                                      \
    asm volatile("s_waitcnt lgkmcnt(" #n ")" ::: "memory"); \
    __builtin_amdgcn_sched_barrier(0);                      \
  } while (0)
#define VMCNT(n) asm volatile("s_waitcnt vmcnt(" #n ")" ::: "memory")

// 16-MFMA cluster: acc[IB..IB+1][0..3], both K-substeps.
template <int IB>
__device__ __forceinline__ void mfma_c2(const i32x4 (&a)[2][2], const i32x4 (&b)[4][2],
                                        i32x4 (&acc)[8][4]) {
#pragma unroll
  for (int i = 0; i < 2; ++i)
#pragma unroll
    for (int j = 0; j < 4; ++j) {
      acc[IB + i][j] =
          __builtin_amdgcn_mfma_i32_16x16x64_i8(a[i][0], b[j][0], acc[IB + i][j], 0, 0, 0);
      acc[IB + i][j] =
          __builtin_amdgcn_mfma_i32_16x16x64_i8(a[i][1], b[j][1], acc[IB + i][j], 0, 0, 0);
    }
}

// ---------------------------------------------------------------------------
// int8 GEMM, 256x256 tile, BK=128, 8 waves (2Mx4N).
// Rebalanced 4-phase schedule (m201-style): every ds_read is issued ONE phase
// before its consuming MFMA cluster and completion is enforced with COUNTED
// lgkmcnt(4) -> ds latency hides across the barrier. Reads/phase: 4/4/4/12,
// the 12 (next tile's a-rows{0,1} + all b) issued AFTER p3's MFMA where the
// registers are dead, consumed after p0's counted wait.
// Clusters are 2 a-rows x 4 b-cols x 2 k-substeps = 16 MFMA/phase.
//
// Staging (4/2/2/0 gload_lds per phase, counted vmcnt(4) once per tile):
//  p0: A(kt+1) both halves  (A-region of that buffer freed at p3(kt-1) endBAR)
//  p1: B(kt+2) half0        (B-region freed at p0(kt) endBAR)
//  p2: B(kt+2) half1; then vmcnt(4) = tile kt+1 fully landed, kt+2's B in
//      flight; BAR publishes -> p3 may read buffer nb.
// Hazards hand-verified: A-region last read completes via lgkm(0)@p3, B-region
// via lgkm(4)@p0; stages to each region are issued only after the barrier
// following those waits.
// ---------------------------------------------------------------------------
__global__ __launch_bounds__(512, 2) void gemm_i8_kernel(
    const signed char* __restrict__ A,   // [M,K] int8 (xq)
    const signed char* __restrict__ Wq,  // [N,K] int8
    const float* __restrict__ sx,        // [M]
    const float* __restrict__ scale,     // [N]
    const float* __restrict__ bias,      // [N]
    float* __restrict__ out) {
  __shared__ __attribute__((aligned(16))) signed char lds[131072];
  signed char* ldsA = &lds[0];      // 2 x 32768
  signed char* ldsB = &lds[65536];  // 2 x 32768

  const int tid = threadIdx.x;
  const int wv = tid >> 6;
  const int ln = tid & 63;
  const int l4 = ln & 15;
  const int hi = ln >> 4;
  const int wm = wv >> 2;  // 0..1
  const int wn = wv & 3;   // 0..3

  // Bijective XCD swizzle (nwg=2048 % 8 == 0): each XCD gets 256 consecutive
  // wg = all 32 mi x 8 ni -> B-panel L2-resident per XCD.
  const int wg = (blockIdx.x & 7) * 256 + (blockIdx.x >> 3);
  const int mi = wg & 31;
  const int ni = wg >> 5;
  const int m0 = mi * 256;
  const int n0 = ni * 256;

  // --- staging geometry (unchanged, verified): thread t -> row t>>3 of the
  // 64-row region, physical slot t&7; global source slot pre-XOR-swizzled.
  const int t8 = tid >> 3;
  const size_t stage_off =
      (size_t)t8 * K_DIM + (size_t)((((tid & 7) ^ ((t8 >> 1) & 7))) << 4);
  const signed char* Asrc = A + (size_t)m0 * K_DIM + stage_off;
  const signed char* Bsrc = Wq + (size_t)n0 * K_DIM + stage_off;

#define STAGE_A(buf, kt, h)                                                      \
  do {                                                                           \
    async_copy16(Asrc + ((size_t)((h) * 128) * K_DIM + (size_t)(kt) * BK),       \
                 ldsA + (buf) * 32768 + (h) * 16384 + wv * 1024);                \
    async_copy16(Asrc + ((size_t)((h) * 128 + 64) * K_DIM + (size_t)(kt) * BK),  \
                 ldsA + (buf) * 32768 + (h) * 16384 + 8192 + wv * 1024);         \
  } while (0)
#define STAGE_B(buf, kt, h)                                                      \
  do {                                                                           \
    async_copy16(Bsrc + ((size_t)((h) * 128) * K_DIM + (size_t)(kt) * BK),       \
                 ldsB + (buf) * 32768 + (h) * 16384 + wv * 1024);                \
    async_copy16(Bsrc + ((size_t)((h) * 128 + 64) * K_DIM + (size_t)(kt) * BK),  \
                 ldsB + (buf) * 32768 + (h) * 16384 + 8192 + wv * 1024);         \
  } while (0)

  // --- fragment read offsets (unchanged, verified). Row r of the wave's
  // region adds r*2048; substep halves at ph0/ph1 with the XOR swizzle.
  const int swz = l4 >> 1;
  const int ph0 = (hi ^ swz) * 16;
  const int ph1 = ((4 + hi) ^ swz) * 16;
  const int aoff0 = (wm * 128 + l4) * 128 + ph0;
  const int aoff1 = (wm * 128 + l4) * 128 + ph1;
  const int boff0 = (wn * 64 + l4) * 128 + ph0;
  const int boff1 = (wn * 64 + l4) * 128 + ph1;

  i32x4 acc[8][4];
#pragma unroll
  for (int i = 0; i < 8; ++i)
#pragma unroll
    for (int j = 0; j < 4; ++j) acc[i][j] = (i32x4){0, 0, 0, 0};
  // aX consumed at p0/p2, aY at p1/p3; reads alternate (p3,p1 -> aX; p0,p2 -> aY)
  i32x4 aX[2][2], aY[2][2], b[4][2];

  // --- prologue: tile0 (8 loads) + B(1) (4 loads); then the "p3" reads.
  STAGE_A(0, 0, 0);
  STAGE_A(0, 0, 1);
  STAGE_B(0, 0, 0);
  STAGE_B(0, 0, 1);
  STAGE_B(1, 1, 0);
  STAGE_B(1, 1, 1);
  VMCNT(4);  // tile0 landed; B(1) in flight
  BAR();
  {
    const signed char* pa0 = ldsA;
    const signed char* pb0 = ldsB;
    aX[0][0] = *(const i32x4*)(pa0 + aoff0 + 0 * 2048);
    aX[0][1] = *(const i32x4*)(pa0 + aoff1 + 0 * 2048);
    aX[1][0] = *(const i32x4*)(pa0 + aoff0 + 1 * 2048);
    aX[1][1] = *(const i32x4*)(pa0 + aoff1 + 1 * 2048);
#pragma unroll
    for (int j = 0; j < 4; ++j) {
      b[j][0] = *(const i32x4*)(pb0 + boff0 + j * 2048);
      b[j][1] = *(const i32x4*)(pb0 + boff1 + j * 2048);
    }
  }
  BAR();

  for (int kt = 0; kt < 32; ++kt) {
    const int q = kt & 1;
    const int nb = q ^ 1;
    const signed char* pa = ldsA + q * 32768;
    const signed char* pb = ldsB + q * 32768;
    const signed char* pan = ldsA + nb * 32768;
    const signed char* pbn = ldsB + nb * 32768;

    // ---- p0: read rows{2,3}->aY ; stage A(kt+1) ; MFMA rows{0,1}(aX)
    aY[0][0] = *(const i32x4*)(pa + aoff0 + 2 * 2048);
    aY[0][1] = *(const i32x4*)(pa + aoff1 + 2 * 2048);
    aY[1][0] = *(const i32x4*)(pa + aoff0 + 3 * 2048);
    aY[1][1] = *(const i32x4*)(pa + aoff1 + 3 * 2048);
    if (kt < 31) {
      STAGE_A(nb, kt + 1, 0);
      STAGE_A(nb, kt + 1, 1);
    }
    BAR();
    LGKM(4);  // p3's 12 reads (aX + b) complete; p0's 4 may be in flight
    __builtin_amdgcn_s_setprio(1);
    mfma_c2<0>(aX, b, acc);
    __builtin_amdgcn_s_setprio(0);
    BAR();

    // ---- p1: read rows{4,5}->aX ; stage B(kt+2,h0) ; MFMA rows{2,3}(aY)
    aX[0][0] = *(const i32x4*)(pa + aoff0 + 4 * 2048);
    aX[0][1] = *(const i32x4*)(pa + aoff1 + 4 * 2048);
    aX[1][0] = *(const i32x4*)(pa + aoff0 + 5 * 2048);
    aX[1][1] = *(const i32x4*)(pa + aoff1 + 5 * 2048);
    if (kt < 30) STAGE_B(q, kt + 2, 0);
    BAR();
    LGKM(4);  // p0's reads complete
    __builtin_amdgcn_s_setprio(1);
    mfma_c2<2>(aY, b, acc);
    __builtin_amdgcn_s_setprio(0);
    BAR();

    // ---- p2: read rows{6,7}->aY ; stage B(kt+2,h1) ; MFMA rows{4,5}(aX)
    aY[0][0] = *(const i32x4*)(pa + aoff0 + 6 * 2048);
    aY[0][1] = *(const i32x4*)(pa + aoff1 + 6 * 2048);
    aY[1][0] = *(const i32x4*)(pa + aoff0 + 7 * 2048);
    aY[1][1] = *(const i32x4*)(pa + aoff1 + 7 * 2048);
    if (kt < 30) STAGE_B(q, kt + 2, 1);
    BAR();
    LGKM(4);  // p1's reads complete
    __builtin_amdgcn_s_setprio(1);
    mfma_c2<4>(aX, b, acc);
    __builtin_amdgcn_s_setprio(0);
    if (kt < 30) {
      VMCNT(4);  // tile kt+1 fully landed; kt+2's B (4 loads) stays in flight
    } else if (kt == 30) {
      VMCNT(0);  // tail drain (A(31) was the last issue)
    }
    BAR();  // publishes vmcnt guarantee -> p3 may read buffer nb

    // ---- p3 (single barrier): MFMA rows{6,7}(aY); then next tile's 12 reads
    LGKM(0);  // p2's reads complete
    __builtin_amdgcn_s_setprio(1);
    mfma_c2<6>(aY, b, acc);
    __builtin_amdgcn_s_setprio(0);
    if (kt < 31) {
      aX[0][0] = *(const i32x4*)(pan + aoff0 + 0 * 2048);
      aX[0][1] = *(const i32x4*)(pan + aoff1 + 0 * 2048);
      aX[1][0] = *(const i32x4*)(pan + aoff0 + 1 * 2048);
      aX[1][1] = *(const i32x4*)(pan + aoff1 + 1 * 2048);
#pragma unroll
      for (int j = 0; j < 4; ++j) {
        b[j][0] = *(const i32x4*)(pbn + boff0 + j * 2048);
        b[j][1] = *(const i32x4*)(pbn + boff1 + j * 2048);
      }
      BAR();  // separates nb-reads from next p0's stage-writes to buf q
    }
  }

  // ---- epilogue (unchanged, verified). C/D: col=l4, row=hi*4+reg.
  int colv[4];
  float sc[4], bi[4];
#pragma unroll
  for (int j = 0; j < 4; ++j) {
    colv[j] = n0 + wn * 64 + j * 16 + l4;
    sc[j] = scale[colv[j]];
    bi[j] = bias[colv[j]];
  }
#pragma unroll
  for (int i = 0; i < 8; ++i) {
    const int rowb = m0 + wm * 128 + i * 16 + hi * 4;
    float sxv[4];
#pragma unroll
    for (int r = 0; r < 4; ++r) sxv[r] = sx[rowb + r];
#pragma unroll
    for (int j = 0; j < 4; ++j)
#pragma unroll
      for (int r = 0; r < 4; ++r)
        out[(size_t)(rowb + r) * N_DIM + colv[j]] =
            (float)acc[i][j][r] * sxv[r] * sc[j] + bi[j];
  }
#undef STAGE_A
#undef STAGE_B
}

// Correctness fallback if workspace is too small (not expected to trigger).
__global__ __launch_bounds__(256) void gemm_fallback(
    const float* __restrict__ X, const int* __restrict__ W,
    const float* __restrict__ scale, const float* __restrict__ bias,
    float* __restrict__ out) {
  __shared__ float Xs[64][17];
  __shared__ float Ws[64][17];
  const int tx = threadIdx.x & 15, ty = threadIdx.x >> 4;
  const int m0 = blockIdx.y * 64, n0 = blockIdx.x * 64;
  float acc[4][4] = {};
  for (int k0 = 0; k0 < K_DIM; k0 += 16) {
    for (int t = threadIdx.x; t < 64 * 16; t += 256) {
      int r = t >> 4, c = t & 15;
      Xs[r][c] = X[(size_t)(m0 + r) * K_DIM + k0 + c];
      Ws[r][c] = (float)W[(size_t)(n0 + r) * K_DIM + k0 + c];
    }
    __syncthreads();
#pragma unroll
    for (int kk = 0; kk < 16; ++kk)
#pragma unroll
      for (int i = 0; i < 4; ++i)
#pragma unroll
        for (int j = 0; j < 4; ++j)
          acc[i][j] += Xs[ty * 4 + i][kk] * Ws[tx * 4 + j][kk];
    __syncthreads();
  }
  for (int i = 0; i < 4; ++i)
    for (int j = 0; j < 4; ++j) {
      int row = m0 + ty * 4 + i, col = n0 + tx * 4 + j;
      out[(size_t)row * N_DIM + col] = acc[i][j] * scale[col] + bias[col];
    }
}

extern "C" void kernel_launch(void* const* d_in, const int* in_sizes, int n_in,
                              void* d_out, int out_size, void* d_ws, size_t ws_size,
                              hipStream_t stream) {
  const float* x = (const float*)d_in[0];
  const int* w8 = (const int*)d_in[1];  // integer inputs arrive as int32
  const float* scale = (const float*)d_in[2];
  const float* bias = (const float*)d_in[3];
  float* out = (float*)d_out;

  const size_t xq_bytes = (size_t)M_DIM * K_DIM;  // int8
  const size_t wq_bytes = (size_t)N_DIM * K_DIM;  // int8
  const size_t sx_bytes = (size_t)M_DIM * sizeof(float);
  const size_t need = xq_bytes + wq_bytes + sx_bytes;

  if (ws_size >= need) {
    signed char* xq = (signed char*)d_ws;
    signed char* wq = xq + xq_bytes;
    float* sx = (float*)(wq + wq_bytes);

    const int cvt_blocks = (int)((wq_bytes / 16 + 255) / 256);
    prep_kernel<<<M_DIM + cvt_blocks, 256, 0, stream>>>(x, (int*)xq, sx, w8, (int*)wq);
    gemm_i8_kernel<<<(M_DIM / 256) * (N_DIM / 256), 512, 0, stream>>>(
        xq, wq, sx, scale, bias, out);
  } else {
    dim3 grid(N_DIM / 64, M_DIM / 64);
    gemm_fallback<<<grid, 256, 0, stream>>>(x, w8, scale, bias, out);
  }
}